// Round 24
// baseline (194.530 us; speedup 1.0000x reference)
//
#include <hip/hip_runtime.h>
#include <hip/hip_bf16.h>
#include <math.h>

// CommNetWork fused MFMA kernel v12, MI355X gfx950. fp32 in / fp32 out.
// v11 post-mortem: hipLaunchCooperativeKernel silently fails under the
// harness's graph capture (out stayed zeroed; absmax 0.78 = max|ref|).
// v12 keeps the row-split occupancy fix (32-row blocks, grid 512 x 512thr
// = 2 blocks/CU = 4 waves/SIMD) but replaces the grid sync with a KERNEL
// BOUNDARY + linearity trick: colsum64(G) = colsum64(H)@W_ih^T, so the
// halves only exchange colsum32(H) (256 f32/block) through ws. Kernel A:
// obs->X1->H, store H(bf16)+partial colsum. Kernel B: reload H half, s =
// part0+part1, S_gate[n] = dot(s, W_ih[n]) (quad-split GEMV), gi/gh MFMAs,
// gates, fused decode (W_fuse from prep). No atomics; every ws slot fully
// rewritten per iteration (re-poison safe).
// [Rounds 22-23: resubmitted verbatim - benches hit GPUAcquisitionTimeout;
//  the v12 experiment has not yet been measured.]

typedef __bf16  bf16x8 __attribute__((ext_vector_type(8)));
typedef float   f32x4  __attribute__((ext_vector_type(4)));

#define DIN 128
#define H0  256
#define SW  264   // padded stride (elems) for 256-wide tiles
#define SWO 136   // padded stride for 128-wide obs tile
#define LOG2E 1.44269504088896f

// ws element offsets (bf16) for converted weight matrices
#define O_WENC  0
#define O_WOBS  32768
#define O_WIH   98304
#define O_WHH   294912
#define O_WFUSE 491520   // 64x256 fused W_dec@W_val
#define NBLK_CONV 240    // converted elems / (256*8)
#define O_BFUSE_B 1015808  // byte offset of b_fuse (f32[64])
#define O_CS_B    1016320  // byte offset: f32 cs[512][256] partial colsums
#define O_H_B     1540608  // byte offset: bf16 H[256][64][256]

__device__ __forceinline__ f32x4 mfma16(bf16x8 a, bf16x8 b, f32x4 c) {
    return __builtin_amdgcn_mfma_f32_16x16x32_bf16(a, b, c, 0, 0, 0);
}
__device__ __forceinline__ float bf2f(__hip_bfloat16 x) { return __bfloat162float(x); }
__device__ __forceinline__ __hip_bfloat16 f2bf(float x) { return __float2bfloat16(x); }

__device__ __forceinline__ float fsigmoid(float x) {
    float e = __builtin_amdgcn_exp2f(-LOG2E * x);
    return __builtin_amdgcn_rcpf(1.0f + e);
}
__device__ __forceinline__ float ftanh(float x) {
    float e = __builtin_amdgcn_exp2f(2.0f * LOG2E * x);
    return 1.0f - 2.0f * __builtin_amdgcn_rcpf(1.0f + e);
}

__device__ __forceinline__ bf16x8 w8(const __hip_bfloat16* p, int idx) {
    return *(const bf16x8*)(p + idx);
}

__device__ __forceinline__ int tadr(int r, int k) { return r * SW + k; }
__device__ __forceinline__ int oadr(int r, int k) { return r * SWO + k; }

// ---- prep: convert 4 weight matrices fp32 -> bf16 (blocks 0..239) and
// ---- compute W_fuse = W_dec @ W_val, b_fuse = W_dec@b_val + b_dec ----
__global__ __launch_bounds__(256) void prep_kernel(
    const float* __restrict__ W_enc, const float* __restrict__ W_obs,
    const float* __restrict__ W_ih,  const float* __restrict__ W_hh,
    const float* __restrict__ W_val, const float* __restrict__ W_dec,
    const float* __restrict__ b_val, const float* __restrict__ b_dec,
    __hip_bfloat16* __restrict__ ws)
{
    const int blk = blockIdx.x;
    const int tid = threadIdx.x;
    if (blk < NBLK_CONV) {
        const int i = (blk * 256 + tid) * 8;
        const float* src; int off;
        if      (i < O_WOBS) { src = W_enc; off = O_WENC; }
        else if (i < O_WIH)  { src = W_obs; off = O_WOBS; }
        else if (i < O_WHH)  { src = W_ih;  off = O_WIH;  }
        else                 { src = W_hh;  off = O_WHH;  }
        const float* f = src + (i - off);
        f32x4 a = *(const f32x4*)f;
        f32x4 b = *(const f32x4*)(f + 4);
        bf16x8 v;
        #pragma unroll
        for (int j = 0; j < 4; j++) { v[j] = (__bf16)a[j]; v[j + 4] = (__bf16)b[j]; }
        *(bf16x8*)(ws + i) = v;
    } else {
        const int o = blk - NBLK_CONV;          // output row 0..63
        __shared__ float wd[256];
        wd[tid] = W_dec[o * 256 + tid];
        __syncthreads();
        float acc = 0.0f;
        #pragma unroll 16
        for (int v = 0; v < 256; v++)
            acc += wd[v] * W_val[v * 256 + tid];
        ws[O_WFUSE + o * 256 + tid] = f2bf(acc);
        if (tid < 64) {
            float p = 0.0f;
            #pragma unroll
            for (int v = tid; v < 256; v += 64) p += wd[v] * b_val[v];
            p += __shfl_xor(p, 32); p += __shfl_xor(p, 16); p += __shfl_xor(p, 8);
            p += __shfl_xor(p, 4);  p += __shfl_xor(p, 2);  p += __shfl_xor(p, 1);
            if (tid == 0) {
                float* bf = (float*)((char*)ws + O_BFUSE_B);
                bf[o] = p + b_dec[o];
            }
        }
    }
}

// ---- kernel A: grid 512, block 512; 32 rows/block: obs -> X1 -> H ----
__global__ __launch_bounds__(512, 2) void commnet_a(
    __hip_bfloat16* __restrict__ ws,
    const float* __restrict__ b_enc, const float* __restrict__ b_obs,
    const float* __restrict__ obs)
{
    __shared__ __align__(16) __hip_bfloat16 T0[32 * SW];  // X1
    __shared__ __align__(16) __hip_bfloat16 T1[32 * SW];  // obs -> H

    const __hip_bfloat16* W_enc = ws + O_WENC;
    const __hip_bfloat16* W_obs = ws + O_WOBS;
    float* cs = (float*)((char*)ws + O_CS_B);
    __hip_bfloat16* Hb = (__hip_bfloat16*)((char*)ws + O_H_B);

    const int tid  = threadIdx.x;
    const int wave = tid >> 6;
    const int lane = tid & 63;
    const int quad = lane >> 4;
    const int lc   = lane & 15;
    const int b    = blockIdx.x >> 1;
    const int half = blockIdx.x & 1;
    const int r0g  = b * 64 + half * 32;
    const int ko16 = quad * 8;

    // ---- stage obs -> bf16 T1 (32x128, 1 chunk/thread) ----
    {
        const int r = tid >> 4;
        const int c = (tid & 15) << 3;
        const float* src = obs + (r0g + r) * DIN + c;
        f32x4 a = *(const f32x4*)src;
        f32x4 bq = *(const f32x4*)(src + 4);
        bf16x8 v;
        #pragma unroll
        for (int j = 0; j < 4; j++) { v[j] = (__bf16)a[j]; v[j + 4] = (__bf16)bq[j]; }
        *(bf16x8*)&T1[oadr(r, c)] = v;
    }
    __syncthreads();

    // ---- stage 1: X1 = relu(obs @ W_enc^T + b_enc) -> T0 ----
    #pragma unroll
    for (int cp = 0; cp < 2; cp++) {
        const int n = (wave + 8 * cp) * 16 + lc;
        const float bias = b_enc[n];
        f32x4 acc[2] = {};
        #pragma unroll
        for (int k0 = 0; k0 < DIN; k0 += 32) {
            const int kk = k0 + ko16;
            bf16x8 bw = w8(W_enc, n * DIN + kk);
            #pragma unroll
            for (int rt = 0; rt < 2; rt++) {
                bf16x8 a = *(const bf16x8*)&T1[oadr(rt * 16 + lc, kk)];
                acc[rt] = mfma16(a, bw, acc[rt]);
            }
        }
        #pragma unroll
        for (int rt = 0; rt < 2; rt++)
            #pragma unroll
            for (int i = 0; i < 4; i++) {
                const int row = rt * 16 + quad * 4 + i;
                T0[tadr(row, n)] = f2bf(fmaxf(acc[rt][i] + bias, 0.0f));
            }
    }
    __syncthreads();

    // ---- stage 2: H = X1 @ W_obs^T + b_obs -> T1 + partial colsum -> cs ----
    #pragma unroll
    for (int cp = 0; cp < 2; cp++) {
        const int n = (wave + 8 * cp) * 16 + lc;
        const float bias = b_obs[n];
        f32x4 acc[2] = {};
        #pragma unroll 4
        for (int k0 = 0; k0 < H0; k0 += 32) {
            const int kk = k0 + ko16;
            bf16x8 bw = w8(W_obs, n * H0 + kk);
            #pragma unroll
            for (int rt = 0; rt < 2; rt++) {
                bf16x8 a = *(const bf16x8*)&T0[tadr(rt * 16 + lc, kk)];
                acc[rt] = mfma16(a, bw, acc[rt]);
            }
        }
        float Sc = 0.0f;
        #pragma unroll
        for (int rt = 0; rt < 2; rt++)
            #pragma unroll
            for (int i = 0; i < 4; i++) {
                const int row = rt * 16 + quad * 4 + i;
                const __hip_bfloat16 hb = f2bf(acc[rt][i] + bias);
                T1[tadr(row, n)] = hb;
                Sc += bf2f(hb);          // colsum of the ROUNDED H (matches MFMA input)
            }
        Sc += __shfl_xor(Sc, 16); Sc += __shfl_xor(Sc, 32);
        if (lane < 16) cs[blockIdx.x * 256 + n] = Sc;
    }
    __syncthreads();

    // ---- copy H half to global (vectorized) ----
    for (int i = tid; i < 32 * H0 / 8; i += 512) {
        const int r = i >> 5;
        const int c = (i & 31) << 3;
        *(bf16x8*)&Hb[(r0g + r) * H0 + c] = *(const bf16x8*)&T1[tadr(r, c)];
    }
}

// ---- kernel B: grid 512, block 512; GRU + fused decode ----
__global__ __launch_bounds__(512, 2) void commnet_b(
    __hip_bfloat16* __restrict__ ws,
    const float* __restrict__ b_ih, const float* __restrict__ b_hh,
    float* __restrict__ out)
{
    __shared__ __align__(16) __hip_bfloat16 T0[32 * SW];  // h'
    __shared__ __align__(16) __hip_bfloat16 T1[32 * SW];  // H
    __shared__ float Ls[256];                             // colsum64(H)

    const __hip_bfloat16* W_ih   = ws + O_WIH;
    const __hip_bfloat16* W_hh   = ws + O_WHH;
    const __hip_bfloat16* W_fuse = ws + O_WFUSE;
    const float* b_fuse = (const float*)((const char*)ws + O_BFUSE_B);
    const float* cs = (const float*)((const char*)ws + O_CS_B);
    const __hip_bfloat16* Hb = (const __hip_bfloat16*)((const char*)ws + O_H_B);

    const int tid  = threadIdx.x;
    const int wave = tid >> 6;
    const int lane = tid & 63;
    const int quad = lane >> 4;
    const int lc   = lane & 15;
    const int b    = blockIdx.x >> 1;
    const int half = blockIdx.x & 1;
    const int r0g  = b * 64 + half * 32;
    const int ko16 = quad * 8;

    // ---- load H half -> T1; s = cs[2b] + cs[2b+1] -> Ls ----
    for (int i = tid; i < 32 * H0 / 8; i += 512) {
        const int r = i >> 5;
        const int c = (i & 31) << 3;
        *(bf16x8*)&T1[tadr(r, c)] = *(const bf16x8*)&Hb[(r0g + r) * H0 + c];
    }
    if (tid < 256)
        Ls[tid] = cs[(b * 2) * 256 + tid] + cs[(b * 2 + 1) * 256 + tid];
    __syncthreads();

    // ---- GRU: per column pass, S_gate GEMV + gi/gh MFMAs + gates -> T0 ----
    #pragma unroll
    for (int cp = 0; cp < 2; cp++) {
        const int n = (wave + 8 * cp) * 16 + lc;
        // S_gate[n] = dot(s, W_ih[n + gate*256]); quad q covers k in [64q,64q+64)
        float Sr = 0.0f, Sz = 0.0f, Sn = 0.0f;
        #pragma unroll
        for (int j0 = 0; j0 < 64; j0 += 8) {
            const int k = quad * 64 + j0;
            bf16x8 wr = w8(W_ih, (n      ) * H0 + k);
            bf16x8 wz = w8(W_ih, (n + 256) * H0 + k);
            bf16x8 wn = w8(W_ih, (n + 512) * H0 + k);
            #pragma unroll
            for (int t = 0; t < 8; t++) {
                const float sv = Ls[k + t];
                Sr += sv * (float)wr[t];
                Sz += sv * (float)wz[t];
                Sn += sv * (float)wn[t];
            }
        }
        Sr += __shfl_xor(Sr, 16); Sr += __shfl_xor(Sr, 32);
        Sz += __shfl_xor(Sz, 16); Sz += __shfl_xor(Sz, 32);
        Sn += __shfl_xor(Sn, 16); Sn += __shfl_xor(Sn, 32);

        const float bir = b_ih[n], biz = b_ih[n + 256], bin = b_ih[n + 512];
        const float bhr = b_hh[n], bhz = b_hh[n + 256], bhn = b_hh[n + 512];
        f32x4 gir[2] = {}, giz[2] = {}, gin[2] = {};
        f32x4 ghr[2] = {}, ghz[2] = {}, ghn[2] = {};
        #pragma unroll 4
        for (int k0 = 0; k0 < H0; k0 += 32) {
            const int kk = k0 + ko16;
            bf16x8 bir8 = w8(W_ih, (n      ) * H0 + kk);
            bf16x8 biz8 = w8(W_ih, (n + 256) * H0 + kk);
            bf16x8 bin8 = w8(W_ih, (n + 512) * H0 + kk);
            bf16x8 bhr8 = w8(W_hh, (n      ) * H0 + kk);
            bf16x8 bhz8 = w8(W_hh, (n + 256) * H0 + kk);
            bf16x8 bhn8 = w8(W_hh, (n + 512) * H0 + kk);
            #pragma unroll
            for (int rt = 0; rt < 2; rt++) {
                bf16x8 aH = *(const bf16x8*)&T1[tadr(rt * 16 + lc, kk)];
                gir[rt] = mfma16(aH, bir8, gir[rt]);
                giz[rt] = mfma16(aH, biz8, giz[rt]);
                gin[rt] = mfma16(aH, bin8, gin[rt]);
                ghr[rt] = mfma16(aH, bhr8, ghr[rt]);
                ghz[rt] = mfma16(aH, bhz8, ghz[rt]);
                ghn[rt] = mfma16(aH, bhn8, ghn[rt]);
            }
        }
        #pragma unroll
        for (int rt = 0; rt < 2; rt++)
            #pragma unroll
            for (int i = 0; i < 4; i++) {
                const int row = rt * 16 + quad * 4 + i;
                const float gi_r = (Sr - gir[rt][i]) * (1.0f / 64.0f) + bir;
                const float gi_z = (Sz - giz[rt][i]) * (1.0f / 64.0f) + biz;
                const float gi_n = (Sn - gin[rt][i]) * (1.0f / 64.0f) + bin;
                const float r  = fsigmoid(gi_r + ghr[rt][i] + bhr);
                const float z  = fsigmoid(gi_z + ghz[rt][i] + bhz);
                const float nn = ftanh(gi_n + r * (ghn[rt][i] + bhn));
                const float h  = bf2f(T1[tadr(row, n)]);
                T0[tadr(row, n)] = f2bf((1.0f - z) * nn + z * h);
            }
    }
    __syncthreads();

    // ---- decode (fused): OUT = h' @ W_fuse^T + b_fuse ----
    {
        const int ct = wave & 3;
        const int rt = wave >> 2;
        const int nd = ct * 16 + lc;
        const float bias = b_fuse[nd];
        f32x4 acc = {};
        #pragma unroll 4
        for (int k0 = 0; k0 < H0; k0 += 32) {
            const int kk = k0 + ko16;
            bf16x8 bw = w8(W_fuse, nd * H0 + kk);
            bf16x8 a = *(const bf16x8*)&T0[tadr(rt * 16 + lc, kk)];
            acc = mfma16(a, bw, acc);
        }
        #pragma unroll
        for (int i = 0; i < 4; i++) {
            const int row = rt * 16 + quad * 4 + i;
            out[(r0g + row) * 64 + nd] = acc[i] + bias;
        }
    }
}

extern "C" void kernel_launch(void* const* d_in, const int* in_sizes, int n_in,
                              void* d_out, int out_size, void* d_ws, size_t ws_size,
                              hipStream_t stream) {
    (void)in_sizes; (void)n_in; (void)out_size; (void)ws_size;
    const float* obs   = (const float*)d_in[0];
    const float* W_enc = (const float*)d_in[1];  const float* b_enc = (const float*)d_in[2];
    const float* W_obs = (const float*)d_in[3];  const float* b_obs = (const float*)d_in[4];
    const float* W_ih  = (const float*)d_in[5];  const float* b_ih  = (const float*)d_in[6];
    const float* W_hh  = (const float*)d_in[7];  const float* b_hh  = (const float*)d_in[8];
    const float* W_val = (const float*)d_in[9];  const float* b_val = (const float*)d_in[10];
    const float* W_dec = (const float*)d_in[11]; const float* b_dec = (const float*)d_in[12];
    float* out = (float*)d_out;
    __hip_bfloat16* ws = (__hip_bfloat16*)d_ws;

    prep_kernel<<<NBLK_CONV + 64, 256, 0, stream>>>(
        W_enc, W_obs, W_ih, W_hh, W_val, W_dec, b_val, b_dec, ws);
    commnet_a<<<512, 512, 0, stream>>>(ws, b_enc, b_obs, obs);
    commnet_b<<<512, 512, 0, stream>>>(ws, b_ih, b_hh, out);
}

// Round 26
// 123.777 us; speedup vs baseline: 1.5716x; 1.5716x over previous
//
#include <hip/hip_runtime.h>
#include <hip/hip_bf16.h>
#include <math.h>

// CommNetWork fused MFMA kernel v13, MI355X gfx950. fp32 in / fp32 out.
// v12 post-mortem: 2-kernel row-split failed (B=97us: no 2/CU co-residency,
// doubled per-CU weight traffic, uncoalesced S_gate GEMV). All occupancy
// levers are now exhausted (1024thr x3 -> 64-VGPR clamp; coop -> no-op;
// split -> regression). v13 = best-of-both verified config: v9's kernel
// (val->dec fusion, GRU unroll 4 = the measured 40.6us) + v10's prep
// (fusion-block unroll 16). Single kernel, 256 blocks x 512 thr, VGPR 116.
// [Round 25: resubmitted verbatim - bench hit GPUAcquisitionTimeout; the
//  v13 experiment has not yet been measured.]

typedef __bf16  bf16x8 __attribute__((ext_vector_type(8)));
typedef float   f32x4  __attribute__((ext_vector_type(4)));

#define DIN 128
#define H0  256
#define SW  264   // padded stride, 256-wide tiles: 132 dwords = 4 mod 32 banks
#define SWO 136   // padded stride, 128-wide obs tile
#define LOG2E 1.44269504088896f

// ws element offsets (bf16) for converted weight matrices
#define O_WENC  0
#define O_WOBS  32768
#define O_WIH   98304
#define O_WHH   294912
#define O_WFUSE 491520   // 64x256 fused W_dec@W_val
#define NBLK_CONV 240    // converted elems / (256*8)
#define O_BFUSE_B 1015808  // byte offset of b_fuse (f32[64]); ws total 1016064 B

__device__ __forceinline__ f32x4 mfma16(bf16x8 a, bf16x8 b, f32x4 c) {
    return __builtin_amdgcn_mfma_f32_16x16x32_bf16(a, b, c, 0, 0, 0);
}
__device__ __forceinline__ float bf2f(__hip_bfloat16 x) { return __bfloat162float(x); }
__device__ __forceinline__ __hip_bfloat16 f2bf(float x) { return __float2bfloat16(x); }

__device__ __forceinline__ float fsigmoid(float x) {
    float e = __builtin_amdgcn_exp2f(-LOG2E * x);
    return __builtin_amdgcn_rcpf(1.0f + e);
}
__device__ __forceinline__ float ftanh(float x) {
    float e = __builtin_amdgcn_exp2f(2.0f * LOG2E * x);
    return 1.0f - 2.0f * __builtin_amdgcn_rcpf(1.0f + e);
}

__device__ __forceinline__ bf16x8 w8(const __hip_bfloat16* p, int idx) {
    return *(const bf16x8*)(p + idx);
}

// affine tile addressing (padded stride)
__device__ __forceinline__ int tadr(int r, int k) { return r * SW + k; }
__device__ __forceinline__ int oadr(int r, int k) { return r * SWO + k; }

// ---- prep: convert 4 weight matrices fp32 -> bf16 (blocks 0..239) and
// ---- compute W_fuse = W_dec @ W_val, b_fuse = W_dec@b_val + b_dec
// ---- (blocks 240..303, one per output row o; unroll 16) ----
__global__ __launch_bounds__(256) void prep_kernel(
    const float* __restrict__ W_enc, const float* __restrict__ W_obs,
    const float* __restrict__ W_ih,  const float* __restrict__ W_hh,
    const float* __restrict__ W_val, const float* __restrict__ W_dec,
    const float* __restrict__ b_val, const float* __restrict__ b_dec,
    __hip_bfloat16* __restrict__ ws)
{
    const int blk = blockIdx.x;
    const int tid = threadIdx.x;
    if (blk < NBLK_CONV) {
        const int i = (blk * 256 + tid) * 8;
        const float* src; int off;
        if      (i < O_WOBS) { src = W_enc; off = O_WENC; }
        else if (i < O_WIH)  { src = W_obs; off = O_WOBS; }
        else if (i < O_WHH)  { src = W_ih;  off = O_WIH;  }
        else                 { src = W_hh;  off = O_WHH;  }
        const float* f = src + (i - off);
        f32x4 a = *(const f32x4*)f;
        f32x4 b = *(const f32x4*)(f + 4);
        bf16x8 v;
        #pragma unroll
        for (int j = 0; j < 4; j++) { v[j] = (__bf16)a[j]; v[j + 4] = (__bf16)b[j]; }
        *(bf16x8*)(ws + i) = v;
    } else {
        // fusion block: o = output row of W_fuse (0..63), tid = column k (0..255)
        const int o = blk - NBLK_CONV;
        __shared__ float wd[256];
        wd[tid] = W_dec[o * 256 + tid];
        __syncthreads();
        float acc = 0.0f;
        #pragma unroll 16
        for (int v = 0; v < 256; v++)
            acc += wd[v] * W_val[v * 256 + tid];   // coalesced over tid
        ws[O_WFUSE + o * 256 + tid] = f2bf(acc);
        if (tid < 64) {
            float p = 0.0f;
            #pragma unroll
            for (int v = tid; v < 256; v += 64) p += wd[v] * b_val[v];
            p += __shfl_xor(p, 32); p += __shfl_xor(p, 16); p += __shfl_xor(p, 8);
            p += __shfl_xor(p, 4);  p += __shfl_xor(p, 2);  p += __shfl_xor(p, 1);
            if (tid == 0) {
                float* bf = (float*)((char*)ws + O_BFUSE_B);
                bf[o] = p + b_dec[o];
            }
        }
    }
}

__global__ __launch_bounds__(512, 2) void commnet_mfma(
    const __hip_bfloat16* __restrict__ ws,
    const float* __restrict__ b_enc, const float* __restrict__ b_obs,
    const float* __restrict__ b_ih,  const float* __restrict__ b_hh,
    const float* __restrict__ obs,   float* __restrict__ out)
{
    __shared__ __align__(16) __hip_bfloat16 T0[64 * SW];  // X1 -> h'
    __shared__ __align__(16) __hip_bfloat16 T1[64 * SW];  // obs -> H

    const __hip_bfloat16* W_enc  = ws + O_WENC;
    const __hip_bfloat16* W_obs  = ws + O_WOBS;
    const __hip_bfloat16* W_ih   = ws + O_WIH;
    const __hip_bfloat16* W_hh   = ws + O_WHH;
    const __hip_bfloat16* W_fuse = ws + O_WFUSE;
    const float* b_fuse = (const float*)((const char*)ws + O_BFUSE_B);

    const int tid  = threadIdx.x;
    const int wave = tid >> 6;
    const int lane = tid & 63;
    const int quad = lane >> 4;
    const int lc   = lane & 15;          // tile col (n) / A-frag row (m)
    const int row0 = blockIdx.x * 64;    // global row base for this batch
    const int ko16 = quad * 8;           // k offset of this lane's fragment

    // ---- stage obs (fp32 global) -> bf16 padded T1 ----
    for (int i = tid; i < 64 * DIN / 8; i += 512) {
        const int r = i >> 4;
        const int c = (i & 15) << 3;
        const float* src = obs + (row0 + r) * DIN + c;
        f32x4 a = *(const f32x4*)src;
        f32x4 b = *(const f32x4*)(src + 4);
        bf16x8 v;
        #pragma unroll
        for (int j = 0; j < 4; j++) { v[j] = (__bf16)a[j]; v[j + 4] = (__bf16)b[j]; }
        *(bf16x8*)&T1[oadr(r, c)] = v;
    }
    __syncthreads();

    // ---- stage 1: X1 = relu(obs @ W_enc^T + b_enc) -> T0 (2 col passes) ----
    #pragma unroll
    for (int cp = 0; cp < 2; cp++) {
        const int n = (wave + 8 * cp) * 16 + lc;
        const float bias = b_enc[n];
        f32x4 acc[4] = {};
        #pragma unroll
        for (int k0 = 0; k0 < DIN; k0 += 32) {
            const int kk = k0 + ko16;
            bf16x8 b = w8(W_enc, n * DIN + kk);
            #pragma unroll
            for (int rt = 0; rt < 4; rt++) {
                bf16x8 a = *(const bf16x8*)&T1[oadr(rt * 16 + lc, kk)];
                acc[rt] = mfma16(a, b, acc[rt]);
            }
        }
        #pragma unroll
        for (int rt = 0; rt < 4; rt++)
            #pragma unroll
            for (int i = 0; i < 4; i++) {
                const int row = rt * 16 + quad * 4 + i;
                T0[tadr(row, n)] = f2bf(fmaxf(acc[rt][i] + bias, 0.0f));
            }
    }
    __syncthreads();

    // ---- stage 2: H = X1 @ W_obs^T + b_obs -> T1 (obs dead) ----
    #pragma unroll
    for (int cp = 0; cp < 2; cp++) {
        const int n = (wave + 8 * cp) * 16 + lc;
        const float bias = b_obs[n];
        f32x4 acc[4] = {};
        #pragma unroll
        for (int k0 = 0; k0 < H0; k0 += 32) {
            const int kk = k0 + ko16;
            bf16x8 b = w8(W_obs, n * H0 + kk);
            #pragma unroll
            for (int rt = 0; rt < 4; rt++) {
                bf16x8 a = *(const bf16x8*)&T0[tadr(rt * 16 + lc, kk)];
                acc[rt] = mfma16(a, b, acc[rt]);
            }
        }
        #pragma unroll
        for (int rt = 0; rt < 4; rt++)
            #pragma unroll
            for (int i = 0; i < 4; i++) {
                const int row = rt * 16 + quad * 4 + i;
                T1[tadr(row, n)] = f2bf(acc[rt][i] + bias);
            }
    }
    __syncthreads();

    // ---- GRU with folded comm (2 col passes, h' -> T0; unroll 4 = v9) ----
    // gi = C@W_ih^T + b_ih with C = (colsum(H) - H)/64; colsum commutes with
    // @W^T, so gi = (colsum(G) - G)/64 + b_ih, G = H@W_ih^T. Each wave owns
    // its 16 columns for all 64 rows: colsum = in-lane sum + shfl_xor(16,32).
    #pragma unroll
    for (int cp = 0; cp < 2; cp++) {
        const int n = (wave + 8 * cp) * 16 + lc;
        const float bir = b_ih[n], biz = b_ih[n + 256], bin = b_ih[n + 512];
        const float bhr = b_hh[n], bhz = b_hh[n + 256], bhn = b_hh[n + 512];
        f32x4 gir[4] = {}, giz[4] = {}, gin[4] = {};
        f32x4 ghr[4] = {}, ghz[4] = {}, ghn[4] = {};
        #pragma unroll 4
        for (int k0 = 0; k0 < H0; k0 += 32) {
            const int kk = k0 + ko16;
            bf16x8 bir8 = w8(W_ih, (n      ) * H0 + kk);
            bf16x8 biz8 = w8(W_ih, (n + 256) * H0 + kk);
            bf16x8 bin8 = w8(W_ih, (n + 512) * H0 + kk);
            bf16x8 bhr8 = w8(W_hh, (n      ) * H0 + kk);
            bf16x8 bhz8 = w8(W_hh, (n + 256) * H0 + kk);
            bf16x8 bhn8 = w8(W_hh, (n + 512) * H0 + kk);
            #pragma unroll
            for (int rt = 0; rt < 4; rt++) {
                bf16x8 aH = *(const bf16x8*)&T1[tadr(rt * 16 + lc, kk)];
                gir[rt] = mfma16(aH, bir8, gir[rt]);
                giz[rt] = mfma16(aH, biz8, giz[rt]);
                gin[rt] = mfma16(aH, bin8, gin[rt]);
                ghr[rt] = mfma16(aH, bhr8, ghr[rt]);
                ghz[rt] = mfma16(aH, bhz8, ghz[rt]);
                ghn[rt] = mfma16(aH, bhn8, ghn[rt]);
            }
        }
        float Sr = 0.0f, Sz = 0.0f, Sn = 0.0f;
        #pragma unroll
        for (int rt = 0; rt < 4; rt++)
            #pragma unroll
            for (int i = 0; i < 4; i++) {
                Sr += gir[rt][i]; Sz += giz[rt][i]; Sn += gin[rt][i];
            }
        Sr += __shfl_xor(Sr, 16); Sr += __shfl_xor(Sr, 32);
        Sz += __shfl_xor(Sz, 16); Sz += __shfl_xor(Sz, 32);
        Sn += __shfl_xor(Sn, 16); Sn += __shfl_xor(Sn, 32);

        #pragma unroll
        for (int rt = 0; rt < 4; rt++)
            #pragma unroll
            for (int i = 0; i < 4; i++) {
                const int row = rt * 16 + quad * 4 + i;
                const float gi_r = (Sr - gir[rt][i]) * (1.0f / 64.0f) + bir;
                const float gi_z = (Sz - giz[rt][i]) * (1.0f / 64.0f) + biz;
                const float gi_n = (Sn - gin[rt][i]) * (1.0f / 64.0f) + bin;
                const float r  = fsigmoid(gi_r + ghr[rt][i] + bhr);
                const float z  = fsigmoid(gi_z + ghz[rt][i] + bhz);
                const float nn = ftanh(gi_n + r * (ghn[rt][i] + bhn));
                const float h  = bf2f(T1[tadr(row, n)]);
                T0[tadr(row, n)] = f2bf((1.0f - z) * nn + z * h);
            }
    }
    __syncthreads();

    // ---- decode (fused): OUT = h' @ W_fuse^T + b_fuse -> global fp32 ----
    {
        const int ct  = wave & 3;          // 4 col-tiles (H2=64)
        const int rtb = (wave >> 2) * 2;   // waves 0-3: rows 0..31, 4-7: 32..63
        const int nd  = ct * 16 + lc;
        const float bias = b_fuse[nd];
        f32x4 acc[2] = {};
        #pragma unroll
        for (int k0 = 0; k0 < H0; k0 += 32) {
            const int kk = k0 + ko16;
            bf16x8 b = w8(W_fuse, nd * H0 + kk);
            #pragma unroll
            for (int j = 0; j < 2; j++) {
                bf16x8 a = *(const bf16x8*)&T0[tadr((rtb + j) * 16 + lc, kk)];
                acc[j] = mfma16(a, b, acc[j]);
            }
        }
        #pragma unroll
        for (int j = 0; j < 2; j++)
            #pragma unroll
            for (int i = 0; i < 4; i++) {
                const int row = (rtb + j) * 16 + quad * 4 + i;
                out[(row0 + row) * 64 + nd] = acc[j][i] + bias;
            }
    }
}

extern "C" void kernel_launch(void* const* d_in, const int* in_sizes, int n_in,
                              void* d_out, int out_size, void* d_ws, size_t ws_size,
                              hipStream_t stream) {
    (void)in_sizes; (void)n_in; (void)out_size; (void)ws_size;
    const float* obs   = (const float*)d_in[0];
    const float* W_enc = (const float*)d_in[1];  const float* b_enc = (const float*)d_in[2];
    const float* W_obs = (const float*)d_in[3];  const float* b_obs = (const float*)d_in[4];
    const float* W_ih  = (const float*)d_in[5];  const float* b_ih  = (const float*)d_in[6];
    const float* W_hh  = (const float*)d_in[7];  const float* b_hh  = (const float*)d_in[8];
    const float* W_val = (const float*)d_in[9];  const float* b_val = (const float*)d_in[10];
    const float* W_dec = (const float*)d_in[11]; const float* b_dec = (const float*)d_in[12];
    float* out = (float*)d_out;
    __hip_bfloat16* ws = (__hip_bfloat16*)d_ws;

    prep_kernel<<<NBLK_CONV + 64, 256, 0, stream>>>(
        W_enc, W_obs, W_ih, W_hh, W_val, W_dec, b_val, b_dec, ws);
    commnet_mfma<<<256, 512, 0, stream>>>(
        ws, b_enc, b_obs, b_ih, b_hh, obs, out);
}